// Round 18
// baseline (245.777 us; speedup 1.0000x reference)
//
#include <hip/hip_runtime.h>
#include <hip/hip_bf16.h>
#include <math.h>

// Problem constants
#define B_  4
#define L_  512
#define H_  1024
#define M_  128
#define E_  64
#define NH_ 16
#define R_  1024
#define D_  768
#define BLK_ 64
#define C_  97
#define NROW (B_*R_)          // 4096
#define KB_  (D_/BLK_)        // 12

typedef __attribute__((ext_vector_type(8))) unsigned short ushort8;
typedef __attribute__((ext_vector_type(4))) unsigned short ushort4v;
typedef __attribute__((ext_vector_type(8))) short s8;       // 8 bf16 MFMA operand
typedef __attribute__((ext_vector_type(4))) float f4;       // MFMA C/D

__device__ __forceinline__ unsigned short f2bf(float x) {   // RNE f32->bf16
    unsigned u = __builtin_bit_cast(unsigned, x);
    unsigned r = (u + 0x7fffu + ((u >> 16) & 1u)) >> 16;
    return (unsigned short)r;
}
__device__ __forceinline__ float bf2f(unsigned short h) {
    unsigned u = ((unsigned)h) << 16;
    return __builtin_bit_cast(float, u);
}
__device__ __forceinline__ float lo16f(unsigned u) { return __builtin_bit_cast(float, u << 16); }
__device__ __forceinline__ float hi16f(unsigned u) { return __builtin_bit_cast(float, u & 0xffff0000u); }

// async global->LDS 16B (compiler never auto-emits; m97 lever). LDS dest
// semantics: wave-uniform base + lane*16 — callers must pass lane-linear lds.
__device__ __forceinline__ void gload_lds16(const unsigned short* g, unsigned short* l)
{
    __builtin_amdgcn_global_load_lds(
        (const __attribute__((address_space(1))) unsigned int*)g,
        (__attribute__((address_space(3))) unsigned int*)l, 16, 0, 0);
}

// ===========================================================================
// R22-verified LAUNCH FUSION (280->244us): 4 launches total.
//   fused_prep: cvt_W | prep_WbT | cvt_seq | pool_lse | pool_attn | out_init
//   fused_mid : gemm_p | gemm_swt | pair_attn
//   gemm_ext, final_mfma: sequential deps.
// ===========================================================================

// ---------------------------------------------------------------------------
// fused_prep — grid.x partitions:
// [0,3072) cvt_W | [3072,3840) prep_WbT | [3840,4864) cvt_seq |
// [4864,5120) pool_lse | [5120,9216) pool_attn | [9216,10768) out_init
// ---------------------------------------------------------------------------
__global__ __launch_bounds__(256) void fused_prep(
    const float* __restrict__ Wh, const float* __restrict__ Wt,
    unsigned short* __restrict__ WhT, unsigned short* __restrict__ WtT,
    const float* __restrict__ Wb, unsigned short* __restrict__ WbT,
    const float* __restrict__ seq_lhs, unsigned short* __restrict__ seqB,
    const float* __restrict__ ent_lhs, const int* __restrict__ labels,
    unsigned short* __restrict__ ent_embB,
    const float* __restrict__ attn, unsigned short* __restrict__ ent_attnB,
    const float* __restrict__ bb, const float* __restrict__ bh,
    const float* __restrict__ bt,
    float* __restrict__ out, float* __restrict__ Ph, float* __restrict__ Pt)
{
    __shared__ __attribute__((aligned(16))) float smem[6208];   // 24832 B scratch
    int bx = blockIdx.x, tid = threadIdx.x;

    if (bx < 3072) {
        // ---- transpose_cvt_W (verbatim)
        int z = bx / 1536, rem = bx % 1536;
        int ky = rem / 24, kx = rem % 24;
        const float* in = z ? Wt : Wh;
        unsigned short* outp = z ? WtT : WhT;
        int n0 = kx*32, k0 = ky*32;
        float (*tile)[33] = (float(*)[33])smem;
        int tx = tid & 31, ty = tid >> 5;
        #pragma unroll
        for (int p = 0; p < 4; ++p)
            tile[ty + p*8][tx] = in[((size_t)(k0 + ty + p*8))*D_ + n0 + tx];
        __syncthreads();
        #pragma unroll
        for (int p = 0; p < 4; ++p) {
            int n = n0 + ty + p*8;
            outp[(size_t)n*2048 + k0 + tx] = f2bf(tile[tx][ty + p*8]);
        }
    } else if (bx < 3840) {
        // ---- prep_WbT (verbatim; R14 frag-packed dense layout)
        int blk = bx - 3072;                 // kb*64 + i
        float* sW = smem;                    // 64*97
        const float* src = Wb + (size_t)blk*64*97;
        for (int e = tid; e < 64*97; e += 256) sW[e] = src[e];
        __syncthreads();
        unsigned short* dst = WbT + (size_t)blk*128*64;
        for (int e = tid; e < 128*64; e += 256) {
            int wcq = e >> 12;
            int ct  = (e >> 10) & 3;
            int j2  = (e >> 9) & 1;
            int qd  = (e >> 7) & 3;
            int lm  = (e >> 3) & 15;
            int t   = e & 7;
            int c   = wcq*64 + ct*16 + lm;
            int j   = j2*32 + qd*8 + t;
            dst[e] = (c < C_) ? f2bf(sW[j*97 + c]) : (unsigned short)0;
        }
    } else if (bx < 4864) {
        // ---- cvt_seq (verbatim)
        size_t i = ((size_t)(bx - 3840)*256 + tid) * 8;
        float4 a = *(const float4*)(seq_lhs + i);
        float4 b = *(const float4*)(seq_lhs + i + 4);
        ushort8 o = { f2bf(a.x), f2bf(a.y), f2bf(a.z), f2bf(a.w),
                      f2bf(b.x), f2bf(b.y), f2bf(b.z), f2bf(b.w) };
        *(ushort8*)(seqB + i) = o;
    } else if (bx < 5120) {
        // ---- pool_lse (verbatim)
        int be = bx - 4864, b = be >> 6, e = be & 63;
        int* midx = (int*)smem;
        int* scnt = (int*)smem + M_;
        if (tid == 0) *scnt = 0;
        __syncthreads();
        if (tid < M_) {
            if (labels[b*M_ + tid] == e) {
                int p = atomicAdd(scnt, 1);
                midx[p] = tid;
            }
        }
        __syncthreads();
        int cnt = *scnt;
        for (int h = tid; h < H_; h += 256) {
            float r = 0.f;
            if (cnt > 0) {
                const float* base = ent_lhs + (size_t)b*M_*H_ + h;
                float mx = -INFINITY;
                for (int k = 0; k < cnt; ++k) mx = fmaxf(mx, base[(size_t)midx[k]*H_]);
                float s = 0.f;
                for (int k = 0; k < cnt; ++k) s += expf(base[(size_t)midx[k]*H_] - mx);
                r = mx + logf(s);
            }
            ent_embB[(size_t)be*H_ + h] = f2bf(r);
        }
    } else if (bx < 9216) {
        // ---- pool_attn (verbatim)
        int id = bx - 5120;
        int e = id & 63, y = id >> 6;
        int b = y >> 4, nh = y & 15;
        int* midx = (int*)smem;
        int* scnt = (int*)smem + M_;
        if (tid == 0) *scnt = 0;
        __syncthreads();
        if (tid < M_) {
            if (labels[b*M_ + tid] == e) {
                int p = atomicAdd(scnt, 1);
                midx[p] = tid;
            }
        }
        __syncthreads();
        int cnt = *scnt;
        float inv = (cnt > 0) ? 1.f/(float)cnt : 0.f;
        const float* base = attn + ((size_t)(b*NH_ + nh)*M_)*L_;
        #pragma unroll
        for (int q = 0; q < 2; ++q) {
            int l = tid + q*256;
            float s = 0.f;
            for (int k = 0; k < cnt; ++k) s += base[(size_t)midx[k]*L_ + l];
            ent_attnB[((size_t)(b*E_ + e)*NH_ + nh)*L_ + l] = f2bf(s * inv);
        }
    } else {
        // ---- out_init (verbatim)
        int i = (bx - 9216)*256 + tid;
        if (i < NROW*C_) out[i] = bb[i % C_];
        if (i < 256*D_) {
            Ph[i] = bh[i % D_];
            Pt[i] = bt[i % D_];
        }
    }
}

// ===========================================================================
// bf16 MFMA GEMM core — R15-verified async global_load_lds staging, R20:
// explicit lda/ldb strides (K-slices via base-ptr offsets; 16B-aligned).
// ===========================================================================
__device__ __forceinline__ void gemm128_core(const unsigned short* __restrict__ A, int lda,
                                             const unsigned short* __restrict__ Bt, int ldb,
                                             int K, int row0, int col0,
                                             f4 (&acc)[4][4])
{
    __shared__ __attribute__((aligned(16))) unsigned short As[128][32];
    __shared__ __attribute__((aligned(16))) unsigned short Bs[128][32];
    int tid = threadIdx.x;
    int wave = tid >> 6, lane = tid & 63;
    int wr = wave & 1, wc = wave >> 1;
    int lm = lane & 15, quad = lane >> 4;

    for (int k0 = 0; k0 < K; k0 += 32) {
        #pragma unroll
        for (int s = 0; s < 2; ++s) {
            int ch = tid + s*256;
            int row = ch >> 2, part = ch & 3;     // lds_byte = ch*16 (lane-linear)
            gload_lds16(A  + (size_t)(row0 + row)*lda + k0 + part*8, &As[0][0] + ch*8);
            gload_lds16(Bt + (size_t)(col0 + row)*ldb + k0 + part*8, &Bs[0][0] + ch*8);
        }
        __syncthreads();   // compiler drains vmcnt(0) before s_barrier
        s8 a[4], b[4];
        #pragma unroll
        for (int ti = 0; ti < 4; ++ti) a[ti] = *(const s8*)&As[wr*64 + ti*16 + lm][quad*8];
        #pragma unroll
        for (int tj = 0; tj < 4; ++tj) b[tj] = *(const s8*)&Bs[wc*64 + tj*16 + lm][quad*8];
        #pragma unroll
        for (int ti = 0; ti < 4; ++ti)
            #pragma unroll
            for (int tj = 0; tj < 4; ++tj)
                acc[ti][tj] = __builtin_amdgcn_mfma_f32_16x16x32_bf16(a[ti], b[tj], acc[ti][tj], 0, 0, 0);
        __syncthreads();
    }
}

// ---------------------------------------------------------------------------
// fused_mid — grid.x partitions:
// [0,96) gemm_p | [96,288) gemm_swt | [288,1312) pair_attn
// ---------------------------------------------------------------------------
__global__ __launch_bounds__(256) void fused_mid(
    const unsigned short* __restrict__ ent_embB,
    const unsigned short* __restrict__ WhT, const unsigned short* __restrict__ WtT,
    float* __restrict__ Ph, float* __restrict__ Pt,
    const unsigned short* __restrict__ seqB, unsigned short* __restrict__ SWT,
    const unsigned short* __restrict__ entA, const int* __restrict__ hts,
    unsigned short* __restrict__ htA)
{
    int bx = blockIdx.x;
    if (bx < 96) {
        // ---- gemm_p (verbatim)
        int x = bx % 6, y = (bx / 6) % 8, z = bx / 48;
        const unsigned short* Bt = z ? WtT : WhT;
        float* P = z ? Pt : Ph;
        int mt = y & 1, ks = y >> 1;
        int row0 = mt*128, col0 = x*128;
        f4 acc[4][4] = {};
        gemm128_core(ent_embB + ks*256, H_, Bt + ks*256, 2048, 256, row0, col0, acc);
        int lane = threadIdx.x & 63, wave = threadIdx.x >> 6;
        int wr = wave & 1, wc = wave >> 1, lm = lane & 15, quad = lane >> 4;
        #pragma unroll
        for (int ti = 0; ti < 4; ++ti)
            #pragma unroll
            for (int tj = 0; tj < 4; ++tj)
                #pragma unroll
                for (int r = 0; r < 4; ++r) {
                    int row = row0 + wr*64 + ti*16 + quad*4 + r;
                    int col = col0 + wc*64 + tj*16 + lm;
                    atomicAdd(P + (size_t)row*D_ + col, acc[ti][tj][r]);
                }
    } else if (bx < 288) {
        // ---- gemm_swt (verbatim)
        int id = bx - 96;
        int x = id % 4, y = (id / 4) % 6, bz = id / 24;
        int z = bz >> 2, b = bz & 3;
        const unsigned short* A  = (z ? WtT : WhT) + 1024;
        const unsigned short* Bt = seqB + (size_t)b*L_*H_;
        int row0 = y*128, col0 = x*128;
        f4 acc[4][4] = {};
        gemm128_core(A, 2048, Bt, H_, H_, row0, col0, acc);
        unsigned short* Cb = SWT + ((size_t)(z*B_ + b)*D_)*L_;
        int lane = threadIdx.x & 63, wave = threadIdx.x >> 6;
        int wr = wave & 1, wc = wave >> 1, lm = lane & 15, quad = lane >> 4;
        #pragma unroll
        for (int ti = 0; ti < 4; ++ti)
            #pragma unroll
            for (int tj = 0; tj < 4; ++tj)
                #pragma unroll
                for (int r = 0; r < 4; ++r) {
                    int d = row0 + wr*64 + ti*16 + quad*4 + r;
                    int l = col0 + wc*64 + tj*16 + lm;
                    Cb[(size_t)d*L_ + l] = f2bf(acc[ti][tj][r]);
                }
    } else {
        // ---- pair_attn (R18-verified wave-per-pair, verbatim)
        int id = bx - 288;
        int w  = threadIdx.x >> 6, ln = threadIdx.x & 63;
        int br = id*4 + w, b = br >> 10;
        int hi = hts[br*2 + 0], ti = hts[br*2 + 1];
        const unsigned* ph = (const unsigned*)(entA + ((size_t)(b*E_ + hi)*NH_)*L_);
        const unsigned* pt = (const unsigned*)(entA + ((size_t)(b*E_ + ti)*NH_)*L_);
        float v0[4] = {0.f, 0.f, 0.f, 0.f};
        float v1[4] = {0.f, 0.f, 0.f, 0.f};
        #pragma unroll
        for (int nh = 0; nh < NH_; ++nh) {
            #pragma unroll
            for (int c = 0; c < 4; ++c) {
                int l2 = ln + c*64;
                unsigned a = ph[nh*(L_/2) + l2], d = pt[nh*(L_/2) + l2];
                v0[c] += lo16f(a)*lo16f(d);
                v1[c] += hi16f(a)*hi16f(d);
            }
        }
        float part = 0.f;
        #pragma unroll
        for (int c = 0; c < 4; ++c) part += v0[c] + v1[c];
        #pragma unroll
        for (int off = 32; off > 0; off >>= 1) part += __shfl_xor(part, off, 64);
        float norm = 1.f / (part*(1.f/16.f) + 1e-5f);
        #pragma unroll
        for (int c = 0; c < 4; ++c) {
            unsigned short o0 = f2bf(v0[c]*(1.f/16.f)*norm);
            unsigned short o1 = f2bf(v1[c]*(1.f/16.f)*norm);
            *(unsigned*)(htA + (size_t)br*L_ + (size_t)(ln + c*64)*2) = ((unsigned)o1 << 16) | o0;
        }
    }
}

// ===========================================================================
// Stage 4b (R21-verified): Q GEMM — Q_z = htA . SWT_z  [4096 x 768], K=512.
// Epilogue: x = Q + P_z[gather] (P carries bias), tanh, bf16 out.
// ===========================================================================
__global__ __launch_bounds__(256) void gemm_ext_mfma(
    const unsigned short* __restrict__ htA,
    const unsigned short* __restrict__ SWT,
    const float* __restrict__ Ph, const float* __restrict__ Pt,
    const int* __restrict__ hts,
    unsigned short* __restrict__ hvB, unsigned short* __restrict__ tvB)
{
    int z = blockIdx.z;
    const float* P = z ? Pt : Ph;
    unsigned short* Cv = z ? tvB : hvB;
    int row0 = blockIdx.y*128, col0 = blockIdx.x*128;
    int b = row0 >> 10;                               // 128-row tiles don't cross b
    const unsigned short* Bt = SWT + ((size_t)(z*B_ + b)*D_)*L_;
    f4 acc[4][4] = {};
    gemm128_core(htA, L_, Bt, L_, L_, row0, col0, acc);
    int lane = threadIdx.x & 63, wave = threadIdx.x >> 6;
    int wr = wave & 1, wc = wave >> 1, lm = lane & 15, quad = lane >> 4;
    #pragma unroll
    for (int ti = 0; ti < 4; ++ti)
        #pragma unroll
        for (int r = 0; r < 4; ++r) {
            int row = row0 + wr*64 + ti*16 + quad*4 + r;
            int idx = hts[row*2 + z];
            const float* prow = P + ((size_t)(b*E_ + idx))*D_;
            #pragma unroll
            for (int tj = 0; tj < 4; ++tj) {
                int col = col0 + wc*64 + tj*16 + lm;
                float x = acc[ti][tj][r] + prow[col];
                float e = __expf(2.f*x);
                Cv[(size_t)row*D_ + col] = f2bf(1.f - 2.f/(e + 1.f));   // tanh
            }
        }
}

// ===========================================================================
// Stage 5b helpers: direct-L2 B-frag load (R14-verified).
// ===========================================================================
__device__ __forceinline__ void loadB_frag(const unsigned short* __restrict__ bbase,
                                           int i, s8 (&dst)[4][2])
{
    #pragma unroll
    for (int ct = 0; ct < 4; ++ct) {
        dst[ct][0] = *(const s8*)(bbase + (size_t)i*8192 + ct*1024);
        dst[ct][1] = *(const s8*)(bbase + (size_t)i*8192 + ct*1024 + 512);
    }
}

// R26-verified (neutral vs R19, numerics identical): packed bf16 tv pairs.
__device__ __forceinline__ void compute_i4p(const s8 (&bfr)[4][2],
                                            const float (&sh)[4],
                                            const unsigned (&tp)[4][2][4],
                                            f4 (&acc)[4][4])
{
    s8 afr[4][2];
    #pragma unroll
    for (int rt = 0; rt < 4; ++rt)
        #pragma unroll
        for (int j2 = 0; j2 < 2; ++j2) {
            union { unsigned u[4]; s8 v; } cv;
            #pragma unroll
            for (int t2 = 0; t2 < 4; ++t2) {
                float pe = sh[rt] * lo16f(tp[rt][j2][t2]);
                float po = sh[rt] * hi16f(tp[rt][j2][t2]);
                cv.u[t2] = __builtin_amdgcn_perm(__builtin_bit_cast(unsigned, po),
                                                 __builtin_bit_cast(unsigned, pe),
                                                 0x07060302u);
            }
            afr[rt][j2] = cv.v;
        }
    #pragma unroll
    for (int ct = 0; ct < 4; ++ct)
        #pragma unroll
        for (int rt = 0; rt < 4; ++rt) {
            acc[rt][ct] = __builtin_amdgcn_mfma_f32_16x16x32_bf16(afr[rt][0], bfr[ct][0], acc[rt][ct], 0, 0, 0);
            acc[rt][ct] = __builtin_amdgcn_mfma_f32_16x16x32_bf16(afr[rt][1], bfr[ct][1], acc[rt][ct], 0, 0, 0);
        }
}

// ===========================================================================
// Stage 5b: block-bilinear classifier — HELD at verified plateau (83-85us).
// Six structural attempts (i-split, sched_barrier, rt=4, LDS-staging x2,
// register-diet) all confirmed the ~85us latency floor: WbT (12MB) exceeds
// the 4MB per-XCD L2, each serial B-load chain pays L3-class latency, and
// neither TLP (scheduler caps ~2 waves/SIMD) nor ILP (compiler sinks
// prefetches in every formulation) hides it at HIP level.
// ===========================================================================
__global__ __launch_bounds__(256) void final_mfma(
    const unsigned short* __restrict__ hvB,   // [4096][768] bf16
    const unsigned short* __restrict__ tvB,
    const unsigned short* __restrict__ WbT,   // [12][64][2][4][2][4][16][8] bf16
    float* __restrict__ out)                  // [4096][97] f32
{
    int kb   = blockIdx.x;
    int row0 = blockIdx.y * 128;
    __shared__ __attribute__((aligned(16))) unsigned short hS[128][72];
    __shared__ __attribute__((aligned(16))) unsigned short tS[128][72];

    int tid = threadIdx.x;
    for (int e = tid; e < 1024; e += 256) {
        int r = e >> 3, part = e & 7;
        *(ushort8*)&hS[r][part*8] = *(const ushort8*)(hvB + (size_t)(row0 + r)*D_ + kb*BLK_ + part*8);
        *(ushort8*)&tS[r][part*8] = *(const ushort8*)(tvB + (size_t)(row0 + r)*D_ + kb*BLK_ + part*8);
    }
    int wave = tid >> 6, lane = tid & 63;
    int wr = wave & 1, wc = wave >> 1;
    int lm = lane & 15, quad = lane >> 4;
    __syncthreads();

    // i-invariant tv fragments as PACKED bf16 pairs (u32 = [lo=even|hi=odd])
    unsigned tp[4][2][4];   // [rowtile][jhalf][t2]
    #pragma unroll
    for (int rt = 0; rt < 4; ++rt)
        #pragma unroll
        for (int j2 = 0; j2 < 2; ++j2) {
            int r = wr*64 + rt*16 + lm;
            const unsigned* w = (const unsigned*)&tS[r][j2*32 + quad*8];
            #pragma unroll
            for (int t2 = 0; t2 < 4; ++t2) tp[rt][j2][t2] = w[t2];
        }

    f4 acc[4][4] = {};
    const unsigned short* bbase = WbT + (size_t)kb*(64*128*64)
                                + (size_t)wc*4096 + ((size_t)quad*16 + lm)*8;

    s8 bufA[4][2], bufB[4][2];
    loadB_frag(bbase, 0, bufA);
    for (int i0 = 0; i0 < 64; i0 += 2) {
        loadB_frag(bbase, i0 + 1, bufB);
        {
            float sh[4];
            #pragma unroll
            for (int rt = 0; rt < 4; ++rt) sh[rt] = bf2f(hS[wr*64 + rt*16 + lm][i0]);
            compute_i4p(bufA, sh, tp, acc);
        }
        if (i0 < 62) loadB_frag(bbase, i0 + 2, bufA);
        {
            float sh[4];
            #pragma unroll
            for (int rt = 0; rt < 4; ++rt) sh[rt] = bf2f(hS[wr*64 + rt*16 + lm][i0 + 1]);
            compute_i4p(bufB, sh, tp, acc);
        }
    }

    #pragma unroll
    for (int rt = 0; rt < 4; ++rt)
        #pragma unroll
        for (int ct = 0; ct < 4; ++ct)
            #pragma unroll
            for (int r = 0; r < 4; ++r) {
                int row = row0 + wr*64 + rt*16 + quad*4 + r;
                int col = wc*64 + ct*16 + lm;
                if (col < C_) atomicAdd(out + (size_t)row*C_ + col, acc[rt][ct][r]);
            }
}

// ===========================================================================
extern "C" void kernel_launch(void* const* d_in, const int* in_sizes, int n_in,
                              void* d_out, int out_size, void* d_ws, size_t ws_size,
                              hipStream_t stream)
{
    const float* seq_lhs = (const float*)d_in[0];
    const float* ent_lhs = (const float*)d_in[1];
    const float* attn    = (const float*)d_in[2];
    const int*   labels  = (const int*)d_in[3];
    const int*   hts     = (const int*)d_in[4];
    const float* Wh      = (const float*)d_in[5];
    const float* bh      = (const float*)d_in[6];
    const float* Wt      = (const float*)d_in[7];
    const float* bt      = (const float*)d_in[8];
    const float* Wb      = (const float*)d_in[9];
    const float* bb      = (const float*)d_in[10];
    float* out = (float*)d_out;

    float* wsf      = (float*)d_ws;
    float* Ph       = wsf;                            // 196608 f32 (256x768)
    float* Pt       = Ph + 196608;                    // 196608 f32
    unsigned short* hvB       = (unsigned short*)(Pt + 196608);  // 3145728 bf16
    unsigned short* tvB       = hvB       + 3145728;  // 3145728
    unsigned short* ent_embB  = tvB       + 3145728;  // 262144
    unsigned short* ent_attnB = ent_embB  + 262144;   // 2097152
    unsigned short* htA       = ent_attnB + 2097152;  // 2097152
    unsigned short* seqB      = htA       + 2097152;  // 2097152 ([b][l][h])
    unsigned short* WhT       = seqB      + 2097152;  // 1572864
    unsigned short* WtT       = WhT       + 1572864;  // 1572864
    unsigned short* SWT       = WtT       + 1572864;  // 3145728 ([z][b][768][512])
    unsigned short* WbT       = SWT       + 3145728;  // 6291456
    // total ~53 MB

    fused_prep<<<10768, 256, 0, stream>>>(Wh, Wt, WhT, WtT, Wb, WbT,
                                          seq_lhs, seqB, ent_lhs, labels, ent_embB,
                                          attn, ent_attnB, bb, bh, bt, out, Ph, Pt);
    fused_mid<<<1312, 256, 0, stream>>>(ent_embB, WhT, WtT, Ph, Pt,
                                        seqB, SWT, ent_attnB, hts, htA);
    gemm_ext_mfma<<<dim3(6, 32, 2), 256, 0, stream>>>(htA, SWT, Ph, Pt, hts, hvB, tvB);
    final_mfma<<<dim3(KB_, NROW/128), 256, 0, stream>>>(hvB, tvB, WbT, out);
}

// Round 19
// 243.585 us; speedup vs baseline: 1.0090x; 1.0090x over previous
//
#include <hip/hip_runtime.h>
#include <hip/hip_bf16.h>
#include <math.h>

// Problem constants
#define B_  4
#define L_  512
#define H_  1024
#define M_  128
#define E_  64
#define NH_ 16
#define R_  1024
#define D_  768
#define BLK_ 64
#define C_  97
#define NROW (B_*R_)          // 4096
#define KB_  (D_/BLK_)        // 12

typedef __attribute__((ext_vector_type(8))) unsigned short ushort8;
typedef __attribute__((ext_vector_type(4))) unsigned short ushort4v;
typedef __attribute__((ext_vector_type(8))) short s8;       // 8 bf16 MFMA operand
typedef __attribute__((ext_vector_type(4))) float f4;       // MFMA C/D

__device__ __forceinline__ unsigned short f2bf(float x) {   // RNE f32->bf16
    unsigned u = __builtin_bit_cast(unsigned, x);
    unsigned r = (u + 0x7fffu + ((u >> 16) & 1u)) >> 16;
    return (unsigned short)r;
}
__device__ __forceinline__ float bf2f(unsigned short h) {
    unsigned u = ((unsigned)h) << 16;
    return __builtin_bit_cast(float, u);
}
__device__ __forceinline__ float lo16f(unsigned u) { return __builtin_bit_cast(float, u << 16); }
__device__ __forceinline__ float hi16f(unsigned u) { return __builtin_bit_cast(float, u & 0xffff0000u); }

// async global->LDS 16B (compiler never auto-emits; m97 lever). LDS dest
// semantics: wave-uniform base + lane*16 — callers must pass lane-linear lds.
__device__ __forceinline__ void gload_lds16(const unsigned short* g, unsigned short* l)
{
    __builtin_amdgcn_global_load_lds(
        (const __attribute__((address_space(1))) unsigned int*)g,
        (__attribute__((address_space(3))) unsigned int*)l, 16, 0, 0);
}

// ===========================================================================
// R22-verified LAUNCH FUSION (280->244us): 4 launches total.
//   fused_prep: cvt_W | prep_WbT | cvt_seq | pool_lse | pool_attn | out_init
//   fused_mid : gemm_p | gemm_swt | pair_attn
//   gemm_ext, final_mfma: sequential deps.
// ===========================================================================

// ---------------------------------------------------------------------------
// fused_prep — grid.x partitions:
// [0,3072) cvt_W | [3072,3840) prep_WbT | [3840,4864) cvt_seq |
// [4864,5120) pool_lse | [5120,9216) pool_attn | [9216,10768) out_init
// ---------------------------------------------------------------------------
__global__ __launch_bounds__(256) void fused_prep(
    const float* __restrict__ Wh, const float* __restrict__ Wt,
    unsigned short* __restrict__ WhT, unsigned short* __restrict__ WtT,
    const float* __restrict__ Wb, unsigned short* __restrict__ WbT,
    const float* __restrict__ seq_lhs, unsigned short* __restrict__ seqB,
    const float* __restrict__ ent_lhs, const int* __restrict__ labels,
    unsigned short* __restrict__ ent_embB,
    const float* __restrict__ attn, unsigned short* __restrict__ ent_attnB,
    const float* __restrict__ bb, const float* __restrict__ bh,
    const float* __restrict__ bt,
    float* __restrict__ out, float* __restrict__ Ph, float* __restrict__ Pt)
{
    __shared__ __attribute__((aligned(16))) float smem[6208];   // 24832 B scratch
    int bx = blockIdx.x, tid = threadIdx.x;

    if (bx < 3072) {
        // ---- transpose_cvt_W (verbatim)
        int z = bx / 1536, rem = bx % 1536;
        int ky = rem / 24, kx = rem % 24;
        const float* in = z ? Wt : Wh;
        unsigned short* outp = z ? WtT : WhT;
        int n0 = kx*32, k0 = ky*32;
        float (*tile)[33] = (float(*)[33])smem;
        int tx = tid & 31, ty = tid >> 5;
        #pragma unroll
        for (int p = 0; p < 4; ++p)
            tile[ty + p*8][tx] = in[((size_t)(k0 + ty + p*8))*D_ + n0 + tx];
        __syncthreads();
        #pragma unroll
        for (int p = 0; p < 4; ++p) {
            int n = n0 + ty + p*8;
            outp[(size_t)n*2048 + k0 + tx] = f2bf(tile[tx][ty + p*8]);
        }
    } else if (bx < 3840) {
        // ---- prep_WbT (verbatim; R14 frag-packed dense layout)
        int blk = bx - 3072;                 // kb*64 + i
        float* sW = smem;                    // 64*97
        const float* src = Wb + (size_t)blk*64*97;
        for (int e = tid; e < 64*97; e += 256) sW[e] = src[e];
        __syncthreads();
        unsigned short* dst = WbT + (size_t)blk*128*64;
        for (int e = tid; e < 128*64; e += 256) {
            int wcq = e >> 12;
            int ct  = (e >> 10) & 3;
            int j2  = (e >> 9) & 1;
            int qd  = (e >> 7) & 3;
            int lm  = (e >> 3) & 15;
            int t   = e & 7;
            int c   = wcq*64 + ct*16 + lm;
            int j   = j2*32 + qd*8 + t;
            dst[e] = (c < C_) ? f2bf(sW[j*97 + c]) : (unsigned short)0;
        }
    } else if (bx < 4864) {
        // ---- cvt_seq (verbatim)
        size_t i = ((size_t)(bx - 3840)*256 + tid) * 8;
        float4 a = *(const float4*)(seq_lhs + i);
        float4 b = *(const float4*)(seq_lhs + i + 4);
        ushort8 o = { f2bf(a.x), f2bf(a.y), f2bf(a.z), f2bf(a.w),
                      f2bf(b.x), f2bf(b.y), f2bf(b.z), f2bf(b.w) };
        *(ushort8*)(seqB + i) = o;
    } else if (bx < 5120) {
        // ---- pool_lse (verbatim)
        int be = bx - 4864, b = be >> 6, e = be & 63;
        int* midx = (int*)smem;
        int* scnt = (int*)smem + M_;
        if (tid == 0) *scnt = 0;
        __syncthreads();
        if (tid < M_) {
            if (labels[b*M_ + tid] == e) {
                int p = atomicAdd(scnt, 1);
                midx[p] = tid;
            }
        }
        __syncthreads();
        int cnt = *scnt;
        for (int h = tid; h < H_; h += 256) {
            float r = 0.f;
            if (cnt > 0) {
                const float* base = ent_lhs + (size_t)b*M_*H_ + h;
                float mx = -INFINITY;
                for (int k = 0; k < cnt; ++k) mx = fmaxf(mx, base[(size_t)midx[k]*H_]);
                float s = 0.f;
                for (int k = 0; k < cnt; ++k) s += expf(base[(size_t)midx[k]*H_] - mx);
                r = mx + logf(s);
            }
            ent_embB[(size_t)be*H_ + h] = f2bf(r);
        }
    } else if (bx < 9216) {
        // ---- pool_attn (verbatim)
        int id = bx - 5120;
        int e = id & 63, y = id >> 6;
        int b = y >> 4, nh = y & 15;
        int* midx = (int*)smem;
        int* scnt = (int*)smem + M_;
        if (tid == 0) *scnt = 0;
        __syncthreads();
        if (tid < M_) {
            if (labels[b*M_ + tid] == e) {
                int p = atomicAdd(scnt, 1);
                midx[p] = tid;
            }
        }
        __syncthreads();
        int cnt = *scnt;
        float inv = (cnt > 0) ? 1.f/(float)cnt : 0.f;
        const float* base = attn + ((size_t)(b*NH_ + nh)*M_)*L_;
        #pragma unroll
        for (int q = 0; q < 2; ++q) {
            int l = tid + q*256;
            float s = 0.f;
            for (int k = 0; k < cnt; ++k) s += base[(size_t)midx[k]*L_ + l];
            ent_attnB[((size_t)(b*E_ + e)*NH_ + nh)*L_ + l] = f2bf(s * inv);
        }
    } else {
        // ---- out_init (verbatim)
        int i = (bx - 9216)*256 + tid;
        if (i < NROW*C_) out[i] = bb[i % C_];
        if (i < 256*D_) {
            Ph[i] = bh[i % D_];
            Pt[i] = bt[i % D_];
        }
    }
}

// ===========================================================================
// bf16 MFMA GEMM core — R15-verified async global_load_lds staging, R20:
// explicit lda/ldb strides (K-slices via base-ptr offsets; 16B-aligned).
// ===========================================================================
__device__ __forceinline__ void gemm128_core(const unsigned short* __restrict__ A, int lda,
                                             const unsigned short* __restrict__ Bt, int ldb,
                                             int K, int row0, int col0,
                                             f4 (&acc)[4][4])
{
    __shared__ __attribute__((aligned(16))) unsigned short As[128][32];
    __shared__ __attribute__((aligned(16))) unsigned short Bs[128][32];
    int tid = threadIdx.x;
    int wave = tid >> 6, lane = tid & 63;
    int wr = wave & 1, wc = wave >> 1;
    int lm = lane & 15, quad = lane >> 4;

    for (int k0 = 0; k0 < K; k0 += 32) {
        #pragma unroll
        for (int s = 0; s < 2; ++s) {
            int ch = tid + s*256;
            int row = ch >> 2, part = ch & 3;     // lds_byte = ch*16 (lane-linear)
            gload_lds16(A  + (size_t)(row0 + row)*lda + k0 + part*8, &As[0][0] + ch*8);
            gload_lds16(Bt + (size_t)(col0 + row)*ldb + k0 + part*8, &Bs[0][0] + ch*8);
        }
        __syncthreads();   // compiler drains vmcnt(0) before s_barrier
        s8 a[4], b[4];
        #pragma unroll
        for (int ti = 0; ti < 4; ++ti) a[ti] = *(const s8*)&As[wr*64 + ti*16 + lm][quad*8];
        #pragma unroll
        for (int tj = 0; tj < 4; ++tj) b[tj] = *(const s8*)&Bs[wc*64 + tj*16 + lm][quad*8];
        #pragma unroll
        for (int ti = 0; ti < 4; ++ti)
            #pragma unroll
            for (int tj = 0; tj < 4; ++tj)
                acc[ti][tj] = __builtin_amdgcn_mfma_f32_16x16x32_bf16(a[ti], b[tj], acc[ti][tj], 0, 0, 0);
        __syncthreads();
    }
}

// ---------------------------------------------------------------------------
// fused_mid — grid.x partitions:
// [0,96) gemm_p | [96,288) gemm_swt | [288,1312) pair_attn
// ---------------------------------------------------------------------------
__global__ __launch_bounds__(256) void fused_mid(
    const unsigned short* __restrict__ ent_embB,
    const unsigned short* __restrict__ WhT, const unsigned short* __restrict__ WtT,
    float* __restrict__ Ph, float* __restrict__ Pt,
    const unsigned short* __restrict__ seqB, unsigned short* __restrict__ SWT,
    const unsigned short* __restrict__ entA, const int* __restrict__ hts,
    unsigned short* __restrict__ htA)
{
    int bx = blockIdx.x;
    if (bx < 96) {
        // ---- gemm_p (verbatim)
        int x = bx % 6, y = (bx / 6) % 8, z = bx / 48;
        const unsigned short* Bt = z ? WtT : WhT;
        float* P = z ? Pt : Ph;
        int mt = y & 1, ks = y >> 1;
        int row0 = mt*128, col0 = x*128;
        f4 acc[4][4] = {};
        gemm128_core(ent_embB + ks*256, H_, Bt + ks*256, 2048, 256, row0, col0, acc);
        int lane = threadIdx.x & 63, wave = threadIdx.x >> 6;
        int wr = wave & 1, wc = wave >> 1, lm = lane & 15, quad = lane >> 4;
        #pragma unroll
        for (int ti = 0; ti < 4; ++ti)
            #pragma unroll
            for (int tj = 0; tj < 4; ++tj)
                #pragma unroll
                for (int r = 0; r < 4; ++r) {
                    int row = row0 + wr*64 + ti*16 + quad*4 + r;
                    int col = col0 + wc*64 + tj*16 + lm;
                    atomicAdd(P + (size_t)row*D_ + col, acc[ti][tj][r]);
                }
    } else if (bx < 288) {
        // ---- gemm_swt (verbatim)
        int id = bx - 96;
        int x = id % 4, y = (id / 4) % 6, bz = id / 24;
        int z = bz >> 2, b = bz & 3;
        const unsigned short* A  = (z ? WtT : WhT) + 1024;
        const unsigned short* Bt = seqB + (size_t)b*L_*H_;
        int row0 = y*128, col0 = x*128;
        f4 acc[4][4] = {};
        gemm128_core(A, 2048, Bt, H_, H_, row0, col0, acc);
        unsigned short* Cb = SWT + ((size_t)(z*B_ + b)*D_)*L_;
        int lane = threadIdx.x & 63, wave = threadIdx.x >> 6;
        int wr = wave & 1, wc = wave >> 1, lm = lane & 15, quad = lane >> 4;
        #pragma unroll
        for (int ti = 0; ti < 4; ++ti)
            #pragma unroll
            for (int tj = 0; tj < 4; ++tj)
                #pragma unroll
                for (int r = 0; r < 4; ++r) {
                    int d = row0 + wr*64 + ti*16 + quad*4 + r;
                    int l = col0 + wc*64 + tj*16 + lm;
                    Cb[(size_t)d*L_ + l] = f2bf(acc[ti][tj][r]);
                }
    } else {
        // ---- pair_attn (R18-verified wave-per-pair, verbatim)
        int id = bx - 288;
        int w  = threadIdx.x >> 6, ln = threadIdx.x & 63;
        int br = id*4 + w, b = br >> 10;
        int hi = hts[br*2 + 0], ti = hts[br*2 + 1];
        const unsigned* ph = (const unsigned*)(entA + ((size_t)(b*E_ + hi)*NH_)*L_);
        const unsigned* pt = (const unsigned*)(entA + ((size_t)(b*E_ + ti)*NH_)*L_);
        float v0[4] = {0.f, 0.f, 0.f, 0.f};
        float v1[4] = {0.f, 0.f, 0.f, 0.f};
        #pragma unroll
        for (int nh = 0; nh < NH_; ++nh) {
            #pragma unroll
            for (int c = 0; c < 4; ++c) {
                int l2 = ln + c*64;
                unsigned a = ph[nh*(L_/2) + l2], d = pt[nh*(L_/2) + l2];
                v0[c] += lo16f(a)*lo16f(d);
                v1[c] += hi16f(a)*hi16f(d);
            }
        }
        float part = 0.f;
        #pragma unroll
        for (int c = 0; c < 4; ++c) part += v0[c] + v1[c];
        #pragma unroll
        for (int off = 32; off > 0; off >>= 1) part += __shfl_xor(part, off, 64);
        float norm = 1.f / (part*(1.f/16.f) + 1e-5f);
        #pragma unroll
        for (int c = 0; c < 4; ++c) {
            unsigned short o0 = f2bf(v0[c]*(1.f/16.f)*norm);
            unsigned short o1 = f2bf(v1[c]*(1.f/16.f)*norm);
            *(unsigned*)(htA + (size_t)br*L_ + (size_t)(ln + c*64)*2) = ((unsigned)o1 << 16) | o0;
        }
    }
}

// ===========================================================================
// Stage 4b (R21-verified): Q GEMM — Q_z = htA . SWT_z  [4096 x 768], K=512.
// Epilogue: x = Q + P_z[gather] (P carries bias), tanh, bf16 out.
// ===========================================================================
__global__ __launch_bounds__(256) void gemm_ext_mfma(
    const unsigned short* __restrict__ htA,
    const unsigned short* __restrict__ SWT,
    const float* __restrict__ Ph, const float* __restrict__ Pt,
    const int* __restrict__ hts,
    unsigned short* __restrict__ hvB, unsigned short* __restrict__ tvB)
{
    int z = blockIdx.z;
    const float* P = z ? Pt : Ph;
    unsigned short* Cv = z ? tvB : hvB;
    int row0 = blockIdx.y*128, col0 = blockIdx.x*128;
    int b = row0 >> 10;                               // 128-row tiles don't cross b
    const unsigned short* Bt = SWT + ((size_t)(z*B_ + b)*D_)*L_;
    f4 acc[4][4] = {};
    gemm128_core(htA, L_, Bt, L_, L_, row0, col0, acc);
    int lane = threadIdx.x & 63, wave = threadIdx.x >> 6;
    int wr = wave & 1, wc = wave >> 1, lm = lane & 15, quad = lane >> 4;
    #pragma unroll
    for (int ti = 0; ti < 4; ++ti)
        #pragma unroll
        for (int r = 0; r < 4; ++r) {
            int row = row0 + wr*64 + ti*16 + quad*4 + r;
            int idx = hts[row*2 + z];
            const float* prow = P + ((size_t)(b*E_ + idx))*D_;
            #pragma unroll
            for (int tj = 0; tj < 4; ++tj) {
                int col = col0 + wc*64 + tj*16 + lm;
                float x = acc[ti][tj][r] + prow[col];
                float e = __expf(2.f*x);
                Cv[(size_t)row*D_ + col] = f2bf(1.f - 2.f/(e + 1.f));   // tanh
            }
        }
}

// ===========================================================================
// Stage 5b helpers: direct-L2 B-frag load (R14-verified).
// ===========================================================================
__device__ __forceinline__ void loadB_frag(const unsigned short* __restrict__ bbase,
                                           int i, s8 (&dst)[4][2])
{
    #pragma unroll
    for (int ct = 0; ct < 4; ++ct) {
        dst[ct][0] = *(const s8*)(bbase + (size_t)i*8192 + ct*1024);
        dst[ct][1] = *(const s8*)(bbase + (size_t)i*8192 + ct*1024 + 512);
    }
}

// R26-verified (neutral vs R19, numerics identical): packed bf16 tv pairs.
__device__ __forceinline__ void compute_i4p(const s8 (&bfr)[4][2],
                                            const float (&sh)[4],
                                            const unsigned (&tp)[4][2][4],
                                            f4 (&acc)[4][4])
{
    s8 afr[4][2];
    #pragma unroll
    for (int rt = 0; rt < 4; ++rt)
        #pragma unroll
        for (int j2 = 0; j2 < 2; ++j2) {
            union { unsigned u[4]; s8 v; } cv;
            #pragma unroll
            for (int t2 = 0; t2 < 4; ++t2) {
                float pe = sh[rt] * lo16f(tp[rt][j2][t2]);
                float po = sh[rt] * hi16f(tp[rt][j2][t2]);
                cv.u[t2] = __builtin_amdgcn_perm(__builtin_bit_cast(unsigned, po),
                                                 __builtin_bit_cast(unsigned, pe),
                                                 0x07060302u);
            }
            afr[rt][j2] = cv.v;
        }
    #pragma unroll
    for (int ct = 0; ct < 4; ++ct)
        #pragma unroll
        for (int rt = 0; rt < 4; ++rt) {
            acc[rt][ct] = __builtin_amdgcn_mfma_f32_16x16x32_bf16(afr[rt][0], bfr[ct][0], acc[rt][ct], 0, 0, 0);
            acc[rt][ct] = __builtin_amdgcn_mfma_f32_16x16x32_bf16(afr[rt][1], bfr[ct][1], acc[rt][ct], 0, 0, 0);
        }
}

// ===========================================================================
// Stage 5b: block-bilinear classifier — HELD at verified plateau (83-85us).
// Six structural attempts (i-split, sched_barrier, rt=4, LDS-staging x2,
// register-diet) all confirmed the ~85us latency floor: the 64 serial
// B-load chains pay L2-hit latency that neither TLP (scheduler caps ~2
// waves/SIMD) nor ILP (compiler sinks prefetches in every formulation)
// hides at HIP level.
// ===========================================================================
__global__ __launch_bounds__(256) void final_mfma(
    const unsigned short* __restrict__ hvB,   // [4096][768] bf16
    const unsigned short* __restrict__ tvB,
    const unsigned short* __restrict__ WbT,   // [12][64][2][4][2][4][16][8] bf16
    float* __restrict__ out)                  // [4096][97] f32
{
    int kb   = blockIdx.x;
    int row0 = blockIdx.y * 128;
    __shared__ __attribute__((aligned(16))) unsigned short hS[128][72];
    __shared__ __attribute__((aligned(16))) unsigned short tS[128][72];

    int tid = threadIdx.x;
    for (int e = tid; e < 1024; e += 256) {
        int r = e >> 3, part = e & 7;
        *(ushort8*)&hS[r][part*8] = *(const ushort8*)(hvB + (size_t)(row0 + r)*D_ + kb*BLK_ + part*8);
        *(ushort8*)&tS[r][part*8] = *(const ushort8*)(tvB + (size_t)(row0 + r)*D_ + kb*BLK_ + part*8);
    }
    int wave = tid >> 6, lane = tid & 63;
    int wr = wave & 1, wc = wave >> 1;
    int lm = lane & 15, quad = lane >> 4;
    __syncthreads();

    // i-invariant tv fragments as PACKED bf16 pairs (u32 = [lo=even|hi=odd])
    unsigned tp[4][2][4];   // [rowtile][jhalf][t2]
    #pragma unroll
    for (int rt = 0; rt < 4; ++rt)
        #pragma unroll
        for (int j2 = 0; j2 < 2; ++j2) {
            int r = wr*64 + rt*16 + lm;
            const unsigned* w = (const unsigned*)&tS[r][j2*32 + quad*8];
            #pragma unroll
            for (int t2 = 0; t2 < 4; ++t2) tp[rt][j2][t2] = w[t2];
        }

    f4 acc[4][4] = {};
    const unsigned short* bbase = WbT + (size_t)kb*(64*128*64)
                                + (size_t)wc*4096 + ((size_t)quad*16 + lm)*8;

    s8 bufA[4][2], bufB[4][2];
    loadB_frag(bbase, 0, bufA);
    for (int i0 = 0; i0 < 64; i0 += 2) {
        loadB_frag(bbase, i0 + 1, bufB);
        {
            float sh[4];
            #pragma unroll
            for (int rt = 0; rt < 4; ++rt) sh[rt] = bf2f(hS[wr*64 + rt*16 + lm][i0]);
            compute_i4p(bufA, sh, tp, acc);
        }
        if (i0 < 62) loadB_frag(bbase, i0 + 2, bufA);
        {
            float sh[4];
            #pragma unroll
            for (int rt = 0; rt < 4; ++rt) sh[rt] = bf2f(hS[wr*64 + rt*16 + lm][i0 + 1]);
            compute_i4p(bufB, sh, tp, acc);
        }
    }

    #pragma unroll
    for (int rt = 0; rt < 4; ++rt)
        #pragma unroll
        for (int ct = 0; ct < 4; ++ct)
            #pragma unroll
            for (int r = 0; r < 4; ++r) {
                int row = row0 + wr*64 + rt*16 + quad*4 + r;
                int col = wc*64 + ct*16 + lm;
                if (col < C_) atomicAdd(out + (size_t)row*C_ + col, acc[rt][ct][r]);
            }
}

// ===========================================================================
extern "C" void kernel_launch(void* const* d_in, const int* in_sizes, int n_in,
                              void* d_out, int out_size, void* d_ws, size_t ws_size,
                              hipStream_t stream)
{
    const float* seq_lhs = (const float*)d_in[0];
    const float* ent_lhs = (const float*)d_in[1];
    const float* attn    = (const float*)d_in[2];
    const int*   labels  = (const int*)d_in[3];
    const int*   hts     = (const int*)d_in[4];
    const float* Wh      = (const float*)d_in[5];
    const float* bh      = (const float*)d_in[6];
    const float* Wt      = (const float*)d_in[7];
    const float* bt      = (const float*)d_in[8];
    const float* Wb      = (const float*)d_in[9];
    const float* bb      = (const float*)d_in[10];
    float* out = (float*)d_out;

    float* wsf      = (float*)d_ws;
    float* Ph       = wsf;                            // 196608 f32 (256x768)
    float* Pt       = Ph + 196608;                    // 196608 f32
    unsigned short* hvB       = (unsigned short*)(Pt + 196608);  // 3145728 bf16
    unsigned short* tvB       = hvB       + 3145728;  // 3145728
    unsigned short* ent_embB  = tvB       + 3145728;  // 262144
    unsigned short* ent_attnB = ent_embB  + 262144;   // 2097152
    unsigned short* htA       = ent_attnB + 2097152;  // 2097152
    unsigned short* seqB      = htA       + 2097152;  // 2097152 ([b][l][h])
    unsigned short* WhT       = seqB      + 2097152;  // 1572864
    unsigned short* WtT       = WhT       + 1572864;  // 1572864
    unsigned short* SWT       = WtT       + 1572864;  // 3145728 ([z][b][768][512])
    unsigned short* WbT       = SWT       + 3145728;  // 6291456
    // total ~53 MB

    fused_prep<<<10768, 256, 0, stream>>>(Wh, Wt, WhT, WtT, Wb, WbT,
                                          seq_lhs, seqB, ent_lhs, labels, ent_embB,
                                          attn, ent_attnB, bb, bh, bt, out, Ph, Pt);
    fused_mid<<<1312, 256, 0, stream>>>(ent_embB, WhT, WtT, Ph, Pt,
                                        seqB, SWT, ent_attnB, hts, htA);
    gemm_ext_mfma<<<dim3(6, 32, 2), 256, 0, stream>>>(htA, SWT, Ph, Pt, hts, hvB, tvB);
    final_mfma<<<dim3(KB_, NROW/128), 256, 0, stream>>>(hvB, tvB, WbT, out);
}